// Round 6
// baseline (184.579 us; speedup 1.0000x reference)
//
#include <hip/hip_runtime.h>
#include <cstdint>
#include <cstddef>

#define NBg 64    // num gt slots
#define NCg 80    // num classes
#define KTOP 10

// CIoU exactly mirroring the reference op order, f32, no FMA contraction.
// atan done in double then rounded -> approximates correctly-rounded f32 libm.
__device__ __forceinline__ float ciou_dev(float gx1, float gy1, float gx2, float gy2,
                                          float px1, float py1, float px2, float py2) {
#pragma clang fp contract(off)
  const float keps = 1e-7f;
  float w1 = gx2 - gx1;
  float h1 = (gy2 - gy1) + keps;
  float w2 = px2 - px1;
  float h2 = (py2 - py1) + keps;
  float iw = fminf(gx2, px2) - fmaxf(gx1, px1);
  float ih = fminf(gy2, py2) - fmaxf(gy1, py1);
  float inter = fmaxf(iw, 0.0f) * fmaxf(ih, 0.0f);
  float uni = w1 * h1 + w2 * h2 - inter + keps;
  float iou = inter / uni;
  float cw = fmaxf(gx2, px2) - fminf(gx1, px1);
  float ch = fmaxf(gy2, py2) - fminf(gy1, py1);
  float c2 = cw * cw + ch * ch + keps;
  float dx = (gx1 + gx2) * 0.5f - (px1 + px2) * 0.5f;
  float dy = (gy1 + gy2) * 0.5f - (py1 + py2) * 0.5f;
  float rho2 = dx * dx + dy * dy;
  float q2 = w2 / h2;
  float q1 = w1 / h1;
  float t = (float)atan((double)q2) - (float)atan((double)q1);
  float v = 0.4052847345693511f * (t * t);
  float alpha = v / ((v - iou) + 1.0000001f);
  return iou - (rho2 / c2 + v * alpha);
}

// am = sqrt(score) * overlap^6 with the exact double-rounded forms used since r1.
__device__ __forceinline__ float am_dev(float sc, float ov) {
  float f1 = (float)sqrt((double)sc);
  double o = (double)ov;
  double o3 = o * o * o;
  return f1 * (float)(o3 * o3);
}

// KA: fused metric + exact top-10 per (b,j) row (jax tie semantics: value desc,
// index asc). One block (4 waves) per row.
// Phase 1: cheap in-box scan; out-of-box enter the per-lane tournament with 0;
//          in-box anchor ids compacted into LDS.
// Phase 2: compact list processed densely (full lane utilization) with
//          CIoU + score gather; entries join the same per-lane tournament.
// Tournament total order is (am desc, idx asc), with exact equality handling,
// so processing order is irrelevant -> identical result to dense scan.
// Emits sel[row][10] = anchor index or -1. Also zero-inits posAlign/posOv.
__global__ void ka_topk(const float* __restrict__ pd_scores,
                        const float* __restrict__ pd_bboxes,
                        const float* __restrict__ anc,
                        const float* __restrict__ gt_labels,
                        const float* __restrict__ gt_bboxes,
                        const int* __restrict__ mask_gt,
                        int* __restrict__ sel,
                        float* __restrict__ posAlign,
                        float* __restrict__ posOv,
                        int NA) {
  int row = blockIdx.x;            // b*64 + j
  int tid = threadIdx.x;
  int lane = tid & 63;
  int wid = tid >> 6;
  if (tid == 0) { posAlign[row] = 0.0f; posOv[row] = 0.0f; }
  if (!mask_gt[row]) {             // block-uniform
    if (tid < KTOP) sel[row * KTOP + tid] = -1;
    return;
  }
  int b = row >> 6;
  const float* g = gt_bboxes + (size_t)row * 4;
  float gx1 = g[0], gy1 = g[1], gx2 = g[2], gy2 = g[3];
  float gl = gt_labels[row];
  int lbl = gl > 0.0f ? (int)gl : 0;
  bool glpos = (gl >= 0.0f);
  const float2* anc2 = (const float2*)anc;

  __shared__ int slist[8400];
  __shared__ int scnt;
  if (tid == 0) scnt = 0;
  __syncthreads();

  float v[KTOP];
  int id[KTOP];
#pragma unroll
  for (int k = 0; k < KTOP; k++) { v[k] = -1.0f; id[k] = 1 << 30; }

  auto ins = [&](float val, int a) {
    if (val > v[KTOP - 1] || (val == v[KTOP - 1] && a < id[KTOP - 1])) {
      v[KTOP - 1] = val; id[KTOP - 1] = a;
#pragma unroll
      for (int k = KTOP - 1; k > 0; k--) {
        bool sw = v[k] > v[k - 1] || (v[k] == v[k - 1] && id[k] < id[k - 1]);
        if (sw) {
          float tv = v[k]; v[k] = v[k - 1]; v[k - 1] = tv;
          int ti = id[k]; id[k] = id[k - 1]; id[k - 1] = ti;
        }
      }
    }
  };

  // Phase 1: cheap scan. Out-of-box -> tournament 0; in-box -> compact.
  for (int a = tid; a < NA; a += 256) {
    float2 ap = anc2[a];
    float dmin = fminf(fminf(ap.x - gx1, ap.y - gy1),
                       fminf(gx2 - ap.x, gy2 - ap.y));
    if (dmin > 1e-9f) {
      int p = atomicAdd(&scnt, 1);
      slist[p] = a;
    } else {
      ins(0.0f, a);
    }
  }
  __syncthreads();
  int nib = scnt;

  // Phase 2: dense CIoU over compacted in-box anchors.
  for (int i = tid; i < nib; i += 256) {
    int a = slist[i];
    const float4 pb = ((const float4*)pd_bboxes)[(size_t)b * NA + a];
    float ci = ciou_dev(gx1, gy1, gx2, gy2, pb.x, pb.y, pb.z, pb.w);
    float ov = ci > 0.0f ? ci : 0.0f;
    float sc = glpos ? pd_scores[((size_t)b * NA + a) * NCg + lbl] : 0.0f;
    ins(am_dev(sc, ov), a);
  }

  // per-wave pop-merge: 10 rounds, winner of round p held by lane p
  float myval = 0.0f; int mysel = 0;
#pragma unroll
  for (int p = 0; p < KTOP; p++) {
    float bv = v[0]; int bi = id[0];
#pragma unroll
    for (int m = 1; m < 64; m <<= 1) {
      float ov_ = __shfl_xor(bv, m, 64);
      int oi = __shfl_xor(bi, m, 64);
      if (ov_ > bv || (ov_ == bv && oi < bi)) { bv = ov_; bi = oi; }
    }
    if (lane == p) { myval = bv; mysel = bi; }
    if (id[0] == bi) {   // this lane owned the winner: pop it
#pragma unroll
      for (int k = 0; k < KTOP - 1; k++) { v[k] = v[k + 1]; id[k] = id[k + 1]; }
      v[KTOP - 1] = -1.0f; id[KTOP - 1] = 1 << 30;
    }
  }

  __shared__ float lv[4 * KTOP];
  __shared__ int li[4 * KTOP];
  if (lane < KTOP) { lv[wid * KTOP + lane] = myval; li[wid * KTOP + lane] = mysel; }
  __syncthreads();
  if (wid != 0) return;

  // final merge of 40 unique-index candidates across wave 0's lanes
  float cv = (lane < 4 * KTOP) ? lv[lane] : -1.0f;
  int ci = (lane < 4 * KTOP) ? li[lane] : (1 << 30);
  int selw = 0;
#pragma unroll
  for (int p = 0; p < KTOP; p++) {
    float bv = cv; int bi = ci;
#pragma unroll
    for (int m = 1; m < 64; m <<= 1) {
      float ov_ = __shfl_xor(bv, m, 64);
      int oi = __shfl_xor(bi, m, 64);
      if (ov_ > bv || (ov_ == bv && oi < bi)) { bv = ov_; bi = oi; }
    }
    if (lane == p) selw = bi;
    if (ci == bi) { cv = -1.0f; ci = 1 << 30; }  // indices unique -> exact pop
  }

  if (lane < KTOP) {
    int a = selw;
    float2 ap = anc2[a];
    float dmin = fminf(fminf(ap.x - gx1, ap.y - gy1),
                       fminf(gx2 - ap.x, gy2 - ap.y));
    sel[row * KTOP + lane] = (dmin > 1e-9f) ? a : -1;  // in-gts filter
  }
}

// K3: per (b,a): build 64-bit gt-match mask from sel lists via LDS scatter,
// resolve multi-matches by first-argmax of overlaps, write target bbox/fg/idx,
// recompute am (bit-identical) and atomic-max posAlign/posOv; stash amv.
__global__ void k3_resolve(const float* __restrict__ pd_scores,
                           const float* __restrict__ pd_bboxes,
                           const float* __restrict__ anc,
                           const float* __restrict__ gt_labels,
                           const float* __restrict__ gt_bboxes,
                           const int* __restrict__ mask_gt,
                           const int* __restrict__ sel,
                           int* __restrict__ tgt,
                           float* __restrict__ amv,
                           float* __restrict__ out_tb,
                           float* __restrict__ out_fg,
                           float* __restrict__ posAlign,
                           float* __restrict__ posOv,
                           int NA) {
  int b = blockIdx.y;
  int tid = threadIdx.x;
  int a0 = blockIdx.x * 256;
  int a = a0 + tid;
  __shared__ float4 sg[NBg];
  __shared__ int svalid[NBg];
  __shared__ int slbl[NBg];
  __shared__ int sglpos[NBg];
  __shared__ unsigned int mlo[256];
  __shared__ unsigned int mhi[256];
  mlo[tid] = 0u; mhi[tid] = 0u;
  if (tid < NBg) {
    int j = tid;
    const float* g = gt_bboxes + ((size_t)b * NBg + j) * 4;
    sg[j] = make_float4(g[0], g[1], g[2], g[3]);
    svalid[j] = mask_gt[b * NBg + j];
    float gl = gt_labels[b * NBg + j];
    slbl[j] = gl > 0.0f ? (int)gl : 0;
    sglpos[j] = (gl >= 0.0f) ? 1 : 0;
  }
  __syncthreads();
  // scatter sel entries of this batch into per-anchor bitmasks
  for (int i = tid; i < NBg * KTOP; i += 256) {
    int e = sel[b * NBg * KTOP + i];
    int d = e - a0;
    if (d >= 0 && d < 256) {
      int j = i / KTOP;
      unsigned int bit = 1u << (j & 31);
      if (j < 32) atomicOr(&mlo[d], bit); else atomicOr(&mhi[d], bit);
    }
  }
  __syncthreads();
  if (a >= NA) return;
  unsigned int lo = mlo[tid], hi = mhi[tid];
  int cnt = __popc(lo) + __popc(hi);
  int first = lo ? (__ffs(lo) - 1) : (hi ? 32 + __ffs(hi) - 1 : 0);

  float ax = anc[2 * a], ay = anc[2 * a + 1];
  float px1 = 0.f, py1 = 0.f, px2 = 0.f, py2 = 0.f;
  if (cnt > 0) {
    const float* pb = pd_bboxes + ((size_t)b * NA + a) * 4;
    px1 = pb[0]; py1 = pb[1]; px2 = pb[2]; py2 = pb[3];
  }
  int t = 0;
  float fg = 0.0f;
  float ovt = -1.0f;
  if (cnt == 1) {
    t = first; fg = 1.0f;
  } else if (cnt > 1) {
    // first-argmax_j overlaps[b,j,a] (jnp.argmax semantics)
    float best = -1.0f;
    for (int jj = 0; jj < NBg; jj++) {
      float ov = 0.0f;
      if (svalid[jj]) {
        float4 g = sg[jj];
        float dmin = fminf(fminf(ax - g.x, ay - g.y), fminf(g.z - ax, g.w - ay));
        if (dmin > 1e-9f) {
          float ci = ciou_dev(g.x, g.y, g.z, g.w, px1, py1, px2, py2);
          ov = ci > 0.0f ? ci : 0.0f;
        }
      }
      if (ov > best) { best = ov; t = jj; }
    }
    fg = 1.0f;
    ovt = best;
  }
  tgt[(size_t)b * NA + a] = t;
  out_fg[(size_t)b * NA + a] = fg;
  float4 gb = sg[t];
  ((float4*)out_tb)[(size_t)b * NA + a] = gb;
  float amval = 0.0f;
  if (fg > 0.0f) {
    float ov;
    if (ovt >= 0.0f) {
      ov = ovt;
    } else {
      float ci = ciou_dev(gb.x, gb.y, gb.z, gb.w, px1, py1, px2, py2);
      ov = ci > 0.0f ? ci : 0.0f;   // t came from sel -> in-box & valid
    }
    float sc = sglpos[t] ? pd_scores[((size_t)b * NA + a) * NCg + slbl[t]] : 0.0f;
    amval = am_dev(sc, ov);
    atomicMax((int*)(posAlign + b * NBg + t), __float_as_int(amval));
    atomicMax((int*)(posOv + b * NBg + t), __float_as_int(ov));
  }
  amv[(size_t)b * NA + a] = amval;
}

// K5: norm + one-hot target_scores, coalesced block-wide writes.
__global__ void k5_scores(const float* __restrict__ gt_labels,
                          const int* __restrict__ tgt,
                          const float* __restrict__ out_fg,
                          const float* __restrict__ amv,
                          const float* __restrict__ posAlign,
                          const float* __restrict__ posOv,
                          float* __restrict__ out_ts,
                          int NA) {
  int b = blockIdx.y;
  int a0 = blockIdx.x * 256;
  int tid = threadIdx.x;
  int a = a0 + tid;
  __shared__ float snorm[256];
  __shared__ int slab[256];
  float norm = 0.0f;
  int lbl = -1;
  if (a < NA) {
    int t = tgt[(size_t)b * NA + a];
    float fg = out_fg[(size_t)b * NA + a];
    if (fg > 0.0f) {
      float av = amv[(size_t)b * NA + a];
      norm = av * posOv[b * NBg + t] / (posAlign[b * NBg + t] + 1e-9f);
      float gl = gt_labels[b * NBg + t];
      lbl = gl > 0.0f ? (int)gl : 0;
    }
  }
  snorm[tid] = norm;
  slab[tid] = lbl;
  __syncthreads();
  int nanch = NA - a0; if (nanch > 256) nanch = 256;
  int nf4 = nanch * (NCg / 4);     // float4s to write for this block
  float4* o = (float4*)(out_ts + ((size_t)b * NA + a0) * NCg);
  for (int i = tid; i < nf4; i += 256) {
    int aa = i / (NCg / 4);
    int c0 = (i % (NCg / 4)) * 4;
    int lb = slab[aa];
    float nv = snorm[aa];
    float4 w = make_float4(0.0f, 0.0f, 0.0f, 0.0f);
    int d = lb - c0;
    if (d >= 0 && d < 4) ((float*)&w)[d] = nv;
    o[i] = w;
  }
}

extern "C" void kernel_launch(void* const* d_in, const int* in_sizes, int n_in,
                              void* d_out, int out_size, void* d_ws, size_t ws_size,
                              hipStream_t stream) {
  const float* pd_scores = (const float*)d_in[0];
  const float* pd_bboxes = (const float*)d_in[1];
  const float* anc       = (const float*)d_in[2];
  const float* gt_labels = (const float*)d_in[3];
  const float* gt_bboxes = (const float*)d_in[4];
  const int*   mask_gt   = (const int*)d_in[5];

  int NA = in_sizes[2] / 2;       // 8400
  int B  = in_sizes[3] / NBg;     // 16
  size_t nBA = (size_t)B * NA;

  float* out_tb = (float*)d_out;              // (B,NA,4)
  float* out_ts = out_tb + nBA * 4;           // (B,NA,80)
  float* out_fg = out_ts + nBA * NCg;         // (B,NA)

  char* ws = (char*)d_ws;
  size_t off = 0;
  int* sel = (int*)(ws + off);                off += (size_t)B * NBg * KTOP * 4;
  int* tgt = (int*)(ws + off);                off += nBA * 4;
  float* amv = (float*)(ws + off);            off += nBA * 4;
  float* posAlign = (float*)(ws + off);       off += (size_t)B * NBg * 4;
  float* posOv = (float*)(ws + off);          off += (size_t)B * NBg * 4;

  dim3 blk(256);
  int rows = B * NBg;                  // 1024 rows, 1 block each
  ka_topk<<<rows, blk, 0, stream>>>(pd_scores, pd_bboxes, anc, gt_labels,
                                    gt_bboxes, mask_gt, sel, posAlign, posOv, NA);
  dim3 gA((NA + 255) / 256, B);
  k3_resolve<<<gA, blk, 0, stream>>>(pd_scores, pd_bboxes, anc, gt_labels,
                                     gt_bboxes, mask_gt, sel, tgt, amv,
                                     out_tb, out_fg, posAlign, posOv, NA);
  k5_scores<<<gA, blk, 0, stream>>>(gt_labels, tgt, out_fg, amv, posAlign, posOv,
                                    out_ts, NA);
}

// Round 7
// 171.218 us; speedup vs baseline: 1.0780x; 1.0780x over previous
//
#include <hip/hip_runtime.h>
#include <cstdint>
#include <cstddef>

#define NBg 64    // num gt slots
#define NCg 80    // num classes
#define KTOP 10
#define K16 16    // padded list size for bitonic merging
#define CAPW 1024 // per-wave compaction capacity (worst-case in-box < 1000 total)

typedef unsigned long long u64k;

// CIoU exactly mirroring the reference op order, f32, no FMA contraction.
// atan done in double then rounded -> approximates correctly-rounded f32 libm.
__device__ __forceinline__ float ciou_dev(float gx1, float gy1, float gx2, float gy2,
                                          float px1, float py1, float px2, float py2) {
#pragma clang fp contract(off)
  const float keps = 1e-7f;
  float w1 = gx2 - gx1;
  float h1 = (gy2 - gy1) + keps;
  float w2 = px2 - px1;
  float h2 = (py2 - py1) + keps;
  float iw = fminf(gx2, px2) - fmaxf(gx1, px1);
  float ih = fminf(gy2, py2) - fmaxf(gy1, py1);
  float inter = fmaxf(iw, 0.0f) * fmaxf(ih, 0.0f);
  float uni = w1 * h1 + w2 * h2 - inter + keps;
  float iou = inter / uni;
  float cw = fmaxf(gx2, px2) - fminf(gx1, px1);
  float ch = fmaxf(gy2, py2) - fminf(gy1, py1);
  float c2 = cw * cw + ch * ch + keps;
  float dx = (gx1 + gx2) * 0.5f - (px1 + px2) * 0.5f;
  float dy = (gy1 + gy2) * 0.5f - (py1 + py2) * 0.5f;
  float rho2 = dx * dx + dy * dy;
  float q2 = w2 / h2;
  float q1 = w1 / h1;
  float t = (float)atan((double)q2) - (float)atan((double)q1);
  float v = 0.4052847345693511f * (t * t);
  float alpha = v / ((v - iou) + 1.0000001f);
  return iou - (rho2 / c2 + v * alpha);
}

// am = sqrt(score) * overlap^6 with the exact double-rounded forms used since r1.
__device__ __forceinline__ float am_dev(float sc, float ov) {
  float f1 = (float)sqrt((double)sc);
  double o = (double)ov;
  double o3 = o * o * o;
  return f1 * (float)(o3 * o3);
}

// key = (float_bits(am) << 32) | ~idx : total order == (am desc, idx asc).
// am >= 0 always -> float bits monotone. Sentinel = 0 (< any real key).
__device__ __forceinline__ u64k mk_key(float am, int a) {
  return ((u64k)__float_as_uint(am) << 32) | (unsigned)(~a);
}

// Merge two sorted-desc 16-lists (unique keys), keep top-16 sorted desc in L.
// Batcher: stage0 C[i] = max(L[i], B[15-i]) isolates top-16 (bitonic),
// then bitonic-merge strides 8,4,2,1 sort it. All indices compile-time.
__device__ __forceinline__ void merge16(u64k (&L)[K16], const u64k (&B)[K16]) {
  u64k C[K16];
#pragma unroll
  for (int i = 0; i < K16; i++) {
    u64k x = L[i], y = B[15 - i];
    C[i] = x > y ? x : y;
  }
#pragma unroll
  for (int s = 8; s > 0; s >>= 1) {
#pragma unroll
    for (int i = 0; i < K16; i++) {
      if ((i & s) == 0) {
        u64k x = C[i], y = C[i | s];
        C[i] = x > y ? x : y;
        C[i | s] = x > y ? y : x;
      }
    }
  }
#pragma unroll
  for (int i = 0; i < K16; i++) L[i] = C[i];
}

// KA: fused metric + exact top-10 per (b,j) row. One block (4 waves) per row.
// Phase 1: batched cheap in-box scan; ballot-compaction into per-wave LDS
//          segment (no atomics); out-of-box anchors enter tournament with 0.
// Phase 2: per-wave dense CIoU over compacted list.
// Merge: per-lane sorted top-10 (u64 keys) -> 6-step butterfly list-merge
//        (registers) -> 2-step cross-wave LDS merge -> lane 0 writes sel.
__global__ void ka_topk(const float* __restrict__ pd_scores,
                        const float* __restrict__ pd_bboxes,
                        const float* __restrict__ anc,
                        const float* __restrict__ gt_labels,
                        const float* __restrict__ gt_bboxes,
                        const int* __restrict__ mask_gt,
                        int* __restrict__ sel,
                        float* __restrict__ posAlign,
                        float* __restrict__ posOv,
                        int NA) {
  int row = blockIdx.x;            // b*64 + j
  int tid = threadIdx.x;
  int lane = tid & 63;
  int wid = tid >> 6;
  if (tid == 0) { posAlign[row] = 0.0f; posOv[row] = 0.0f; }
  if (!mask_gt[row]) {             // block-uniform
    if (tid < KTOP) sel[row * KTOP + tid] = -1;
    return;
  }
  int b = row >> 6;
  const float* g = gt_bboxes + (size_t)row * 4;
  float gx1 = g[0], gy1 = g[1], gx2 = g[2], gy2 = g[3];
  float gl = gt_labels[row];
  int lbl = gl > 0.0f ? (int)gl : 0;
  bool glpos = (gl >= 0.0f);
  const float2* anc2 = (const float2*)anc;

  __shared__ int slist[4 * CAPW];
  __shared__ u64k xl[4][K16];

  u64k k[KTOP];
#pragma unroll
  for (int q = 0; q < KTOP; q++) k[q] = 0;

  auto ins = [&](u64k key) {
    if (key > k[KTOP - 1]) {
      k[KTOP - 1] = key;
#pragma unroll
      for (int q = KTOP - 1; q > 0; q--) {
        if (k[q] > k[q - 1]) { u64k t = k[q]; k[q] = k[q - 1]; k[q - 1] = t; }
      }
    }
  };

  auto heavy = [&](int a) {        // full metric for one in-box anchor
    const float4 pb = ((const float4*)pd_bboxes)[(size_t)b * NA + a];
    float ci = ciou_dev(gx1, gy1, gx2, gy2, pb.x, pb.y, pb.z, pb.w);
    float ov = ci > 0.0f ? ci : 0.0f;
    float sc = glpos ? pd_scores[((size_t)b * NA + a) * NCg + lbl] : 0.0f;
    ins(mk_key(am_dev(sc, ov), a));
  };

  // Phase 1: 9 batches of 4 strided anchors, loads issued up-front per batch.
  int wcnt = 0;                    // wave-uniform running count
  u64k lmask_lt = (1ull << lane) - 1;
#pragma unroll
  for (int itb = 0; itb < 9; itb++) {
    float2 p[4];
    int idx[4];
#pragma unroll
    for (int u = 0; u < 4; u++) {
      idx[u] = tid + (itb * 4 + u) * 256;
      p[u] = (idx[u] < NA) ? anc2[idx[u]] : make_float2(0.0f, 0.0f);
    }
#pragma unroll
    for (int u = 0; u < 4; u++) {
      bool valid = idx[u] < NA;
      float dmin = fminf(fminf(p[u].x - gx1, p[u].y - gy1),
                         fminf(gx2 - p[u].x, gy2 - p[u].y));
      bool inbox = valid && (dmin > 1e-9f);
      u64k m = __ballot(inbox);
      if (inbox) {
        int pos = wcnt + __popcll(m & lmask_lt);
        if (pos < CAPW) slist[wid * CAPW + pos] = idx[u];
        else heavy(idx[u]);        // overflow fallback (never in practice)
      } else if (valid) {
        ins((u64k)(unsigned)(~idx[u]));  // am == 0 entry
      }
      wcnt += __popcll(m);
    }
  }
  int wslots = wcnt < CAPW ? wcnt : CAPW;

  // Phase 2: dense metric over this wave's compacted list.
  for (int i = lane; i < wslots; i += 64) heavy(slist[wid * CAPW + i]);

  // Expand sorted top-10 to 16-list (sentinel-padded).
  u64k L[K16];
#pragma unroll
  for (int q = 0; q < KTOP; q++) L[q] = k[q];
#pragma unroll
  for (int q = KTOP; q < K16; q++) L[q] = 0;

  // 6-step butterfly: after this, every lane holds the wave's sorted top-16.
#pragma unroll
  for (int step = 0; step < 6; step++) {
    u64k B[K16];
#pragma unroll
    for (int q = 0; q < K16; q++)
      B[q] = __shfl_xor((unsigned long long)L[q], 1 << step, 64);
    merge16(L, B);
  }

  // Cross-wave merge via LDS broadcast lists.
  if (lane < K16) xl[wid][lane] = L[lane];
  __syncthreads();
  if (wid == 2) {                  // 2 <- merge(2,3)
    u64k B[K16];
#pragma unroll
    for (int q = 0; q < K16; q++) B[q] = xl[3][q];
    merge16(L, B);
    if (lane < K16) xl[2][lane] = L[lane];
  }
  if (wid == 0) {                  // 0 <- merge(0,1)
    u64k B[K16];
#pragma unroll
    for (int q = 0; q < K16; q++) B[q] = xl[1][q];
    merge16(L, B);
  }
  __syncthreads();
  if (wid == 0) {
    u64k B[K16];
#pragma unroll
    for (int q = 0; q < K16; q++) B[q] = xl[2][q];
    merge16(L, B);                 // global top-16, sorted
    if (lane == 0) {
#pragma unroll
      for (int q = 0; q < KTOP; q++) {
        int a = ~((unsigned)L[q]);
        float2 ap = anc2[a];
        float dmin = fminf(fminf(ap.x - gx1, ap.y - gy1),
                           fminf(gx2 - ap.x, gy2 - ap.y));
        sel[row * KTOP + q] = (dmin > 1e-9f) ? a : -1;  // in-gts filter
      }
    }
  }
}

// K3: per (b,a): build 64-bit gt-match mask from sel lists via LDS scatter,
// resolve multi-matches by first-argmax of overlaps, write target bbox/fg/idx,
// recompute am (bit-identical) and atomic-max posAlign/posOv; stash amv.
__global__ void k3_resolve(const float* __restrict__ pd_scores,
                           const float* __restrict__ pd_bboxes,
                           const float* __restrict__ anc,
                           const float* __restrict__ gt_labels,
                           const float* __restrict__ gt_bboxes,
                           const int* __restrict__ mask_gt,
                           const int* __restrict__ sel,
                           int* __restrict__ tgt,
                           float* __restrict__ amv,
                           float* __restrict__ out_tb,
                           float* __restrict__ out_fg,
                           float* __restrict__ posAlign,
                           float* __restrict__ posOv,
                           int NA) {
  int b = blockIdx.y;
  int tid = threadIdx.x;
  int a0 = blockIdx.x * 256;
  int a = a0 + tid;
  __shared__ float4 sg[NBg];
  __shared__ int svalid[NBg];
  __shared__ int slbl[NBg];
  __shared__ int sglpos[NBg];
  __shared__ unsigned int mlo[256];
  __shared__ unsigned int mhi[256];
  mlo[tid] = 0u; mhi[tid] = 0u;
  if (tid < NBg) {
    int j = tid;
    const float* g = gt_bboxes + ((size_t)b * NBg + j) * 4;
    sg[j] = make_float4(g[0], g[1], g[2], g[3]);
    svalid[j] = mask_gt[b * NBg + j];
    float gl = gt_labels[b * NBg + j];
    slbl[j] = gl > 0.0f ? (int)gl : 0;
    sglpos[j] = (gl >= 0.0f) ? 1 : 0;
  }
  __syncthreads();
  // scatter sel entries of this batch into per-anchor bitmasks
  for (int i = tid; i < NBg * KTOP; i += 256) {
    int e = sel[b * NBg * KTOP + i];
    int d = e - a0;
    if (d >= 0 && d < 256) {
      int j = i / KTOP;
      unsigned int bit = 1u << (j & 31);
      if (j < 32) atomicOr(&mlo[d], bit); else atomicOr(&mhi[d], bit);
    }
  }
  __syncthreads();
  if (a >= NA) return;
  unsigned int lo = mlo[tid], hi = mhi[tid];
  int cnt = __popc(lo) + __popc(hi);
  int first = lo ? (__ffs(lo) - 1) : (hi ? 32 + __ffs(hi) - 1 : 0);

  float ax = anc[2 * a], ay = anc[2 * a + 1];
  float px1 = 0.f, py1 = 0.f, px2 = 0.f, py2 = 0.f;
  if (cnt > 0) {
    const float* pb = pd_bboxes + ((size_t)b * NA + a) * 4;
    px1 = pb[0]; py1 = pb[1]; px2 = pb[2]; py2 = pb[3];
  }
  int t = 0;
  float fg = 0.0f;
  float ovt = -1.0f;
  if (cnt == 1) {
    t = first; fg = 1.0f;
  } else if (cnt > 1) {
    // first-argmax_j overlaps[b,j,a] (jnp.argmax semantics)
    float best = -1.0f;
    for (int jj = 0; jj < NBg; jj++) {
      float ov = 0.0f;
      if (svalid[jj]) {
        float4 g = sg[jj];
        float dmin = fminf(fminf(ax - g.x, ay - g.y), fminf(g.z - ax, g.w - ay));
        if (dmin > 1e-9f) {
          float ci = ciou_dev(g.x, g.y, g.z, g.w, px1, py1, px2, py2);
          ov = ci > 0.0f ? ci : 0.0f;
        }
      }
      if (ov > best) { best = ov; t = jj; }
    }
    fg = 1.0f;
    ovt = best;
  }
  tgt[(size_t)b * NA + a] = t;
  out_fg[(size_t)b * NA + a] = fg;
  float4 gb = sg[t];
  ((float4*)out_tb)[(size_t)b * NA + a] = gb;
  float amval = 0.0f;
  if (fg > 0.0f) {
    float ov;
    if (ovt >= 0.0f) {
      ov = ovt;
    } else {
      float ci = ciou_dev(gb.x, gb.y, gb.z, gb.w, px1, py1, px2, py2);
      ov = ci > 0.0f ? ci : 0.0f;   // t came from sel -> in-box & valid
    }
    float sc = sglpos[t] ? pd_scores[((size_t)b * NA + a) * NCg + slbl[t]] : 0.0f;
    amval = am_dev(sc, ov);
    atomicMax((int*)(posAlign + b * NBg + t), __float_as_int(amval));
    atomicMax((int*)(posOv + b * NBg + t), __float_as_int(ov));
  }
  amv[(size_t)b * NA + a] = amval;
}

// K5: norm + one-hot target_scores, coalesced block-wide writes.
__global__ void k5_scores(const float* __restrict__ gt_labels,
                          const int* __restrict__ tgt,
                          const float* __restrict__ out_fg,
                          const float* __restrict__ amv,
                          const float* __restrict__ posAlign,
                          const float* __restrict__ posOv,
                          float* __restrict__ out_ts,
                          int NA) {
  int b = blockIdx.y;
  int a0 = blockIdx.x * 256;
  int tid = threadIdx.x;
  int a = a0 + tid;
  __shared__ float snorm[256];
  __shared__ int slab[256];
  float norm = 0.0f;
  int lbl = -1;
  if (a < NA) {
    int t = tgt[(size_t)b * NA + a];
    float fg = out_fg[(size_t)b * NA + a];
    if (fg > 0.0f) {
      float av = amv[(size_t)b * NA + a];
      norm = av * posOv[b * NBg + t] / (posAlign[b * NBg + t] + 1e-9f);
      float gl = gt_labels[b * NBg + t];
      lbl = gl > 0.0f ? (int)gl : 0;
    }
  }
  snorm[tid] = norm;
  slab[tid] = lbl;
  __syncthreads();
  int nanch = NA - a0; if (nanch > 256) nanch = 256;
  int nf4 = nanch * (NCg / 4);     // float4s to write for this block
  float4* o = (float4*)(out_ts + ((size_t)b * NA + a0) * NCg);
  for (int i = tid; i < nf4; i += 256) {
    int aa = i / (NCg / 4);
    int c0 = (i % (NCg / 4)) * 4;
    int lb = slab[aa];
    float nv = snorm[aa];
    float4 w = make_float4(0.0f, 0.0f, 0.0f, 0.0f);
    int d = lb - c0;
    if (d >= 0 && d < 4) ((float*)&w)[d] = nv;
    o[i] = w;
  }
}

extern "C" void kernel_launch(void* const* d_in, const int* in_sizes, int n_in,
                              void* d_out, int out_size, void* d_ws, size_t ws_size,
                              hipStream_t stream) {
  const float* pd_scores = (const float*)d_in[0];
  const float* pd_bboxes = (const float*)d_in[1];
  const float* anc       = (const float*)d_in[2];
  const float* gt_labels = (const float*)d_in[3];
  const float* gt_bboxes = (const float*)d_in[4];
  const int*   mask_gt   = (const int*)d_in[5];

  int NA = in_sizes[2] / 2;       // 8400
  int B  = in_sizes[3] / NBg;     // 16
  size_t nBA = (size_t)B * NA;

  float* out_tb = (float*)d_out;              // (B,NA,4)
  float* out_ts = out_tb + nBA * 4;           // (B,NA,80)
  float* out_fg = out_ts + nBA * NCg;         // (B,NA)

  char* ws = (char*)d_ws;
  size_t off = 0;
  int* sel = (int*)(ws + off);                off += (size_t)B * NBg * KTOP * 4;
  int* tgt = (int*)(ws + off);                off += nBA * 4;
  float* amv = (float*)(ws + off);            off += nBA * 4;
  float* posAlign = (float*)(ws + off);       off += (size_t)B * NBg * 4;
  float* posOv = (float*)(ws + off);          off += (size_t)B * NBg * 4;

  dim3 blk(256);
  int rows = B * NBg;                  // 1024 rows, 1 block each
  ka_topk<<<rows, blk, 0, stream>>>(pd_scores, pd_bboxes, anc, gt_labels,
                                    gt_bboxes, mask_gt, sel, posAlign, posOv, NA);
  dim3 gA((NA + 255) / 256, B);
  k3_resolve<<<gA, blk, 0, stream>>>(pd_scores, pd_bboxes, anc, gt_labels,
                                     gt_bboxes, mask_gt, sel, tgt, amv,
                                     out_tb, out_fg, posAlign, posOv, NA);
  k5_scores<<<gA, blk, 0, stream>>>(gt_labels, tgt, out_fg, amv, posAlign, posOv,
                                    out_ts, NA);
}

// Round 8
// 158.353 us; speedup vs baseline: 1.1656x; 1.0812x over previous
//
#include <hip/hip_runtime.h>
#include <cstdint>
#include <cstddef>

#define NBg 64    // num gt slots
#define NCg 80    // num classes
#define KTOP 10
#define K16 16    // padded list size for bitonic merging

typedef unsigned long long u64k;

// CIoU exactly mirroring the reference op order, f32, no FMA contraction.
// atan done in double then rounded -> approximates correctly-rounded f32 libm.
__device__ __forceinline__ float ciou_dev(float gx1, float gy1, float gx2, float gy2,
                                          float px1, float py1, float px2, float py2) {
#pragma clang fp contract(off)
  const float keps = 1e-7f;
  float w1 = gx2 - gx1;
  float h1 = (gy2 - gy1) + keps;
  float w2 = px2 - px1;
  float h2 = (py2 - py1) + keps;
  float iw = fminf(gx2, px2) - fmaxf(gx1, px1);
  float ih = fminf(gy2, py2) - fmaxf(gy1, py1);
  float inter = fmaxf(iw, 0.0f) * fmaxf(ih, 0.0f);
  float uni = w1 * h1 + w2 * h2 - inter + keps;
  float iou = inter / uni;
  float cw = fmaxf(gx2, px2) - fminf(gx1, px1);
  float ch = fmaxf(gy2, py2) - fminf(gy1, py1);
  float c2 = cw * cw + ch * ch + keps;
  float dx = (gx1 + gx2) * 0.5f - (px1 + px2) * 0.5f;
  float dy = (gy1 + gy2) * 0.5f - (py1 + py2) * 0.5f;
  float rho2 = dx * dx + dy * dy;
  float q2 = w2 / h2;
  float q1 = w1 / h1;
  float t = (float)atan((double)q2) - (float)atan((double)q1);
  float v = 0.4052847345693511f * (t * t);
  float alpha = v / ((v - iou) + 1.0000001f);
  return iou - (rho2 / c2 + v * alpha);
}

// am = sqrt(score) * overlap^6 with the exact double-rounded forms used since r1.
__device__ __forceinline__ float am_dev(float sc, float ov) {
  float f1 = (float)sqrt((double)sc);
  double o = (double)ov;
  double o3 = o * o * o;
  return f1 * (float)(o3 * o3);
}

// key = (float_bits(am) << 32) | ~idx : total order == (am desc, idx asc).
// am >= 0 always -> float bits monotone. Sentinel = 0 (< any real key).
__device__ __forceinline__ u64k mk_key(float am, int a) {
  return ((u64k)__float_as_uint(am) << 32) | (unsigned)(~a);
}

// Merge two sorted-desc 16-lists (unique keys), keep top-16 sorted desc in L.
__device__ __forceinline__ void merge16(u64k (&L)[K16], const u64k (&B)[K16]) {
  u64k C[K16];
#pragma unroll
  for (int i = 0; i < K16; i++) {
    u64k x = L[i], y = B[15 - i];
    C[i] = x > y ? x : y;
  }
#pragma unroll
  for (int s = 8; s > 0; s >>= 1) {
#pragma unroll
    for (int i = 0; i < K16; i++) {
      if ((i & s) == 0) {
        u64k x = C[i], y = C[i | s];
        C[i] = x > y ? x : y;
        C[i | s] = x > y ? y : x;
      }
    }
  }
#pragma unroll
  for (int i = 0; i < K16; i++) L[i] = C[i];
}

// KA: fused metric + exact top-10 per (b,j) row. One block (4 waves) per row.
// Anchors form a regular grid -> in-box candidates are 3 index rectangles
// (conservative ranges; exact float dmin test filters). ~260 candidates get
// the heavy metric at full lane utilization; no full-anchor scan.
// Positives sort first in key order; tail slots are filled with the
// smallest-index zero-am anchors (exact jax.lax.top_k tie semantics).
__global__ void ka_topk(const float* __restrict__ pd_scores,
                        const float* __restrict__ pd_bboxes,
                        const float* __restrict__ anc,
                        const float* __restrict__ gt_labels,
                        const float* __restrict__ gt_bboxes,
                        const int* __restrict__ mask_gt,
                        int* __restrict__ sel,
                        float* __restrict__ posAlign,
                        float* __restrict__ posOv,
                        int NA) {
  int row = blockIdx.x;            // b*64 + j
  int tid = threadIdx.x;
  int lane = tid & 63;
  int wid = tid >> 6;
  if (tid == 0) { posAlign[row] = 0.0f; posOv[row] = 0.0f; }
  if (!mask_gt[row]) {             // block-uniform
    if (tid < KTOP) sel[row * KTOP + tid] = -1;
    return;
  }
  int b = row >> 6;
  const float* g = gt_bboxes + (size_t)row * 4;
  float gx1 = g[0], gy1 = g[1], gx2 = g[2], gy2 = g[3];
  float gl = gt_labels[row];
  int lbl = gl > 0.0f ? (int)gl : 0;
  bool glpos = (gl >= 0.0f);

  // conservative candidate rectangles per level (slack +-1, clamped)
  auto rect = [&](float s, int n, int& x0, int& y0, int& w, int& h) {
    int i0 = (int)floorf(gx1 / s - 0.5f) - 1; if (i0 < 0) i0 = 0;
    int i1 = (int)ceilf (gx2 / s - 0.5f) + 1; if (i1 > n - 1) i1 = n - 1;
    int j0 = (int)floorf(gy1 / s - 0.5f) - 1; if (j0 < 0) j0 = 0;
    int j1 = (int)ceilf (gy2 / s - 0.5f) + 1; if (j1 > n - 1) j1 = n - 1;
    x0 = i0; y0 = j0;
    w = i1 - i0 + 1; h = j1 - j0 + 1;
    if (w < 0) w = 0;
    if (h < 0) h = 0;
  };
  int x00, y00, w0, h0, x01, y01, w1, h1, x02, y02, w2, h2;
  rect( 8.0f, 80, x00, y00, w0, h0);
  rect(16.0f, 40, x01, y01, w1, h1);
  rect(32.0f, 20, x02, y02, w2, h2);
  int sz0 = w0 * h0, sz1 = w1 * h1, sz2 = w2 * h2;
  int tot = sz0 + sz1 + sz2;

  u64k k[KTOP];
#pragma unroll
  for (int q = 0; q < KTOP; q++) k[q] = 0;

  auto ins = [&](u64k key) {
    if (key > k[KTOP - 1]) {
      k[KTOP - 1] = key;
#pragma unroll
      for (int q = KTOP - 1; q > 0; q--) {
        if (k[q] > k[q - 1]) { u64k t = k[q]; k[q] = k[q - 1]; k[q - 1] = t; }
      }
    }
  };

  for (int c = tid; c < tot; c += 256) {
    int cc, x0, y0, w, nbase, ngrid; float ss;
    if (c < sz0)              { cc = c;              x0 = x00; y0 = y00; w = w0; nbase = 0;    ngrid = 80; ss =  8.0f; }
    else if (c < sz0 + sz1)   { cc = c - sz0;        x0 = x01; y0 = y01; w = w1; nbase = 6400; ngrid = 40; ss = 16.0f; }
    else                      { cc = c - sz0 - sz1;  x0 = x02; y0 = y02; w = w2; nbase = 8000; ngrid = 20; ss = 32.0f; }
    int iy = y0 + cc / w;
    int ix = x0 + cc % w;
    float ax = ((float)ix + 0.5f) * ss;   // bit-identical to stored anc
    float ay = ((float)iy + 0.5f) * ss;
    float dmin = fminf(fminf(ax - gx1, ay - gy1), fminf(gx2 - ax, gy2 - ay));
    if (dmin > 1e-9f) {
      int a = nbase + iy * ngrid + ix;
      const float4 pb = ((const float4*)pd_bboxes)[(size_t)b * NA + a];
      float ci = ciou_dev(gx1, gy1, gx2, gy2, pb.x, pb.y, pb.z, pb.w);
      float ov = ci > 0.0f ? ci : 0.0f;
      float sc = glpos ? pd_scores[((size_t)b * NA + a) * NCg + lbl] : 0.0f;
      ins(mk_key(am_dev(sc, ov), a));
    }
  }

  // Expand sorted top-10 to 16-list (sentinel-padded).
  u64k L[K16];
#pragma unroll
  for (int q = 0; q < KTOP; q++) L[q] = k[q];
#pragma unroll
  for (int q = KTOP; q < K16; q++) L[q] = 0;

  // 6-step butterfly: every lane ends with the wave's sorted top-16.
#pragma unroll
  for (int step = 0; step < 6; step++) {
    u64k B[K16];
#pragma unroll
    for (int q = 0; q < K16; q++)
      B[q] = __shfl_xor((unsigned long long)L[q], 1 << step, 64);
    merge16(L, B);
  }

  // Cross-wave merge via LDS broadcast lists.
  __shared__ u64k xl[4][K16];
  if (lane < K16) xl[wid][lane] = L[lane];
  __syncthreads();
  if (wid == 2) {                  // 2 <- merge(2,3)
    u64k B[K16];
#pragma unroll
    for (int q = 0; q < K16; q++) B[q] = xl[3][q];
    merge16(L, B);
    if (lane < K16) xl[2][lane] = L[lane];
  }
  if (wid == 0) {                  // 0 <- merge(0,1)
    u64k B[K16];
#pragma unroll
    for (int q = 0; q < K16; q++) B[q] = xl[1][q];
    merge16(L, B);
  }
  __syncthreads();
  if (wid == 0) {
    u64k B[K16];
#pragma unroll
    for (int q = 0; q < K16; q++) B[q] = xl[2][q];
    merge16(L, B);                 // global top-16, sorted desc
    if (lane == 0) {
      // positives (am > 0) are a strict prefix of L
      int npos = 0;
#pragma unroll
      for (int q = 0; q < KTOP; q++) if ((L[q] >> 32) != 0) npos++;
      int cand = 0;
      const float2* anc2 = (const float2*)anc;
      for (int slot = 0; slot < KTOP; slot++) {
        int a;
        if (slot < npos) {
          a = (int)~(unsigned)L[slot];
        } else {
          // smallest index not among the positive set
          bool moved = true;
          while (moved) {
            moved = false;
#pragma unroll
            for (int q = 0; q < KTOP; q++)
              if (q < npos && (int)~(unsigned)L[q] == cand) { cand++; moved = true; }
          }
          a = cand++;
        }
        float2 ap = anc2[a];
        float dmin = fminf(fminf(ap.x - gx1, ap.y - gy1),
                           fminf(gx2 - ap.x, gy2 - ap.y));
        sel[row * KTOP + slot] = (dmin > 1e-9f) ? a : -1;  // in-gts filter
      }
    }
  }
}

// K3: per (b,a): build 64-bit gt-match mask from sel lists via LDS scatter,
// resolve multi-matches by first-argmax of overlaps (cheap in-box mask first,
// CIoU only on set bits), write target bbox/fg/idx, recompute am and
// atomic-max posAlign/posOv; stash amv.
__global__ void k3_resolve(const float* __restrict__ pd_scores,
                           const float* __restrict__ pd_bboxes,
                           const float* __restrict__ anc,
                           const float* __restrict__ gt_labels,
                           const float* __restrict__ gt_bboxes,
                           const int* __restrict__ mask_gt,
                           const int* __restrict__ sel,
                           int* __restrict__ tgt,
                           float* __restrict__ amv,
                           float* __restrict__ out_tb,
                           float* __restrict__ out_fg,
                           float* __restrict__ posAlign,
                           float* __restrict__ posOv,
                           int NA) {
  int b = blockIdx.y;
  int tid = threadIdx.x;
  int a0 = blockIdx.x * 256;
  int a = a0 + tid;
  __shared__ float4 sg[NBg];
  __shared__ int svalid[NBg];
  __shared__ int slbl[NBg];
  __shared__ int sglpos[NBg];
  __shared__ unsigned int mlo[256];
  __shared__ unsigned int mhi[256];
  mlo[tid] = 0u; mhi[tid] = 0u;
  if (tid < NBg) {
    int j = tid;
    const float* g = gt_bboxes + ((size_t)b * NBg + j) * 4;
    sg[j] = make_float4(g[0], g[1], g[2], g[3]);
    svalid[j] = mask_gt[b * NBg + j];
    float gl = gt_labels[b * NBg + j];
    slbl[j] = gl > 0.0f ? (int)gl : 0;
    sglpos[j] = (gl >= 0.0f) ? 1 : 0;
  }
  __syncthreads();
  // scatter sel entries of this batch into per-anchor bitmasks
  for (int i = tid; i < NBg * KTOP; i += 256) {
    int e = sel[b * NBg * KTOP + i];
    int d = e - a0;
    if (d >= 0 && d < 256) {
      int j = i / KTOP;
      unsigned int bit = 1u << (j & 31);
      if (j < 32) atomicOr(&mlo[d], bit); else atomicOr(&mhi[d], bit);
    }
  }
  __syncthreads();
  if (a >= NA) return;
  unsigned int lo = mlo[tid], hi = mhi[tid];
  int cnt = __popc(lo) + __popc(hi);
  int first = lo ? (__ffs(lo) - 1) : (hi ? 32 + __ffs(hi) - 1 : 0);

  float ax = anc[2 * a], ay = anc[2 * a + 1];
  float px1 = 0.f, py1 = 0.f, px2 = 0.f, py2 = 0.f;
  if (cnt > 0) {
    const float* pb = pd_bboxes + ((size_t)b * NA + a) * 4;
    px1 = pb[0]; py1 = pb[1]; px2 = pb[2]; py2 = pb[3];
  }
  int t = 0;
  float fg = 0.0f;
  float ovt = -1.0f;
  if (cnt == 1) {
    t = first; fg = 1.0f;
  } else if (cnt > 1) {
    // cheap pass: in-box & valid j bitmask (no CIoU)
    unsigned bm_lo = 0u, bm_hi = 0u;
    for (int jj = 0; jj < NBg; jj++) {
      if (svalid[jj]) {
        float4 gq = sg[jj];
        float dmin = fminf(fminf(ax - gq.x, ay - gq.y), fminf(gq.z - ax, gq.w - ay));
        if (dmin > 1e-9f) {
          if (jj < 32) bm_lo |= 1u << jj; else bm_hi |= 1u << (jj - 32);
        }
      }
    }
    // first-argmax over overlaps: CIoU only on set bits (ascending)
    float best = 0.0f;                      // zeros elsewhere -> argmax 0 default
    t = 0;
    unsigned m = bm_lo; int base = 0;
    for (int half = 0; half < 2; half++) {
      while (m) {
        int jj = base + __ffs(m) - 1; m &= m - 1;
        float4 gq = sg[jj];
        float ci = ciou_dev(gq.x, gq.y, gq.z, gq.w, px1, py1, px2, py2);
        float ov = ci > 0.0f ? ci : 0.0f;
        if (ov > best) { best = ov; t = jj; }
      }
      m = bm_hi; base = 32;
    }
    fg = 1.0f;
    ovt = best;
  }
  tgt[(size_t)b * NA + a] = t;
  out_fg[(size_t)b * NA + a] = fg;
  float4 gb = sg[t];
  ((float4*)out_tb)[(size_t)b * NA + a] = gb;
  float amval = 0.0f;
  if (fg > 0.0f) {
    float ov;
    if (ovt >= 0.0f) {
      ov = ovt;
    } else {
      float ci = ciou_dev(gb.x, gb.y, gb.z, gb.w, px1, py1, px2, py2);
      ov = ci > 0.0f ? ci : 0.0f;   // t came from sel -> in-box & valid
    }
    float sc = sglpos[t] ? pd_scores[((size_t)b * NA + a) * NCg + slbl[t]] : 0.0f;
    amval = am_dev(sc, ov);
    atomicMax((int*)(posAlign + b * NBg + t), __float_as_int(amval));
    atomicMax((int*)(posOv + b * NBg + t), __float_as_int(ov));
  }
  amv[(size_t)b * NA + a] = amval;
}

// K5: norm + one-hot target_scores, coalesced block-wide writes.
__global__ void k5_scores(const float* __restrict__ gt_labels,
                          const int* __restrict__ tgt,
                          const float* __restrict__ out_fg,
                          const float* __restrict__ amv,
                          const float* __restrict__ posAlign,
                          const float* __restrict__ posOv,
                          float* __restrict__ out_ts,
                          int NA) {
  int b = blockIdx.y;
  int a0 = blockIdx.x * 256;
  int tid = threadIdx.x;
  int a = a0 + tid;
  __shared__ float snorm[256];
  __shared__ int slab[256];
  float norm = 0.0f;
  int lbl = -1;
  if (a < NA) {
    int t = tgt[(size_t)b * NA + a];
    float fg = out_fg[(size_t)b * NA + a];
    if (fg > 0.0f) {
      float av = amv[(size_t)b * NA + a];
      norm = av * posOv[b * NBg + t] / (posAlign[b * NBg + t] + 1e-9f);
      float gl = gt_labels[b * NBg + t];
      lbl = gl > 0.0f ? (int)gl : 0;
    }
  }
  snorm[tid] = norm;
  slab[tid] = lbl;
  __syncthreads();
  int nanch = NA - a0; if (nanch > 256) nanch = 256;
  int nf4 = nanch * (NCg / 4);     // float4s to write for this block
  float4* o = (float4*)(out_ts + ((size_t)b * NA + a0) * NCg);
  for (int i = tid; i < nf4; i += 256) {
    int aa = i / (NCg / 4);
    int c0 = (i % (NCg / 4)) * 4;
    int lb = slab[aa];
    float nv = snorm[aa];
    float4 w = make_float4(0.0f, 0.0f, 0.0f, 0.0f);
    int d = lb - c0;
    if (d >= 0 && d < 4) ((float*)&w)[d] = nv;
    o[i] = w;
  }
}

extern "C" void kernel_launch(void* const* d_in, const int* in_sizes, int n_in,
                              void* d_out, int out_size, void* d_ws, size_t ws_size,
                              hipStream_t stream) {
  const float* pd_scores = (const float*)d_in[0];
  const float* pd_bboxes = (const float*)d_in[1];
  const float* anc       = (const float*)d_in[2];
  const float* gt_labels = (const float*)d_in[3];
  const float* gt_bboxes = (const float*)d_in[4];
  const int*   mask_gt   = (const int*)d_in[5];

  int NA = in_sizes[2] / 2;       // 8400
  int B  = in_sizes[3] / NBg;     // 16
  size_t nBA = (size_t)B * NA;

  float* out_tb = (float*)d_out;              // (B,NA,4)
  float* out_ts = out_tb + nBA * 4;           // (B,NA,80)
  float* out_fg = out_ts + nBA * NCg;         // (B,NA)

  char* ws = (char*)d_ws;
  size_t off = 0;
  int* sel = (int*)(ws + off);                off += (size_t)B * NBg * KTOP * 4;
  int* tgt = (int*)(ws + off);                off += nBA * 4;
  float* amv = (float*)(ws + off);            off += nBA * 4;
  float* posAlign = (float*)(ws + off);       off += (size_t)B * NBg * 4;
  float* posOv = (float*)(ws + off);          off += (size_t)B * NBg * 4;

  dim3 blk(256);
  int rows = B * NBg;                  // 1024 rows, 1 block each
  ka_topk<<<rows, blk, 0, stream>>>(pd_scores, pd_bboxes, anc, gt_labels,
                                    gt_bboxes, mask_gt, sel, posAlign, posOv, NA);
  dim3 gA((NA + 255) / 256, B);
  k3_resolve<<<gA, blk, 0, stream>>>(pd_scores, pd_bboxes, anc, gt_labels,
                                     gt_bboxes, mask_gt, sel, tgt, amv,
                                     out_tb, out_fg, posAlign, posOv, NA);
  k5_scores<<<gA, blk, 0, stream>>>(gt_labels, tgt, out_fg, amv, posAlign, posOv,
                                    out_ts, NA);
}